// Round 13
// baseline (102.472 us; speedup 1.0000x reference)
//
#include <hip/hip_runtime.h>
#include <hip/hip_bf16.h>
#include <stdint.h>

// Problem constants
#define BB 8
#define CC 64
#define NN 16384
#define KNB 8            // neighbors
// Padded GEMM1 K (REPERMUTED): cols kk*64+c = feature[c][idx[kk]] for kk=0..7,
// cols 512..519 = dis[0..7], cols 520..543 = 0.  (17 kb-steps of 32)

typedef __attribute__((ext_vector_type(8))) short   s16x8;
typedef __attribute__((ext_vector_type(4))) short   s16x4;
typedef __attribute__((ext_vector_type(8))) __bf16  bf16x8;
typedef __attribute__((ext_vector_type(4))) float   f32x4;

__device__ __forceinline__ unsigned short f2bf(float f) {
    unsigned u = __builtin_bit_cast(unsigned, f);
    u = (u + 0x7FFFu + ((u >> 16) & 1u)) >> 16;   // RNE, inputs finite
    return (unsigned short)u;
}

__device__ __forceinline__ int getq(const int4& q, int j) {
    return j == 0 ? q.x : j == 1 ? q.y : j == 2 ? q.z : q.w;   // j constant-folds after unroll
}

// ---- workspace layout (bytes) ----
#define OFF_DISB  16777216u
#define OFF_W1B   18874368u
#define OFF_W2B   19013632u
#define OFF_W3B   19046400u

// ---------------- merged prep: featT transpose + dis->bf16 + weights frag-major ----------------
__global__ __launch_bounds__(256) void prep_all(
    const float* __restrict__ feat, const float* __restrict__ dis,
    const float* __restrict__ W1, const float* __restrict__ W2, const float* __restrict__ W3,
    unsigned short* __restrict__ featT, unsigned short* __restrict__ disB,
    unsigned short* __restrict__ w1p, unsigned short* __restrict__ w2p,
    unsigned short* __restrict__ w3p)
{
    const int bid = blockIdx.x;
    if (bid < 512) {
        int gt = bid * 256 + threadIdx.x;          // global point 0..131071
        int b = gt >> 14, n = gt & 16383;
        const float* fp = feat + ((size_t)b << 20) + n;
        unsigned short v[64];
        #pragma unroll
        for (int c = 0; c < 64; ++c) v[c] = f2bf(fp[(size_t)c << 14]);  // coalesced across lanes
        unsigned short* dst = featT + (size_t)gt * 64;
        #pragma unroll
        for (int j = 0; j < 8; ++j) {
            s16x8 pk;
            #pragma unroll
            for (int i = 0; i < 8; ++i) pk[i] = (short)v[j * 8 + i];
            *(s16x8*)(dst + j * 8) = pk;
        }
        return;
    }
    int tid = (bid - 512) * 256 + threadIdx.x;
    if (tid < 131072) {                        // one POINT per thread: 8 dis values
        const float* dp = dis + (size_t)tid * 8;
        s16x8 pk;
        #pragma unroll
        for (int j = 0; j < 8; ++j) pk[j] = (short)f2bf(dp[j]);
        *(s16x8*)(disB + (size_t)tid * 8) = pk;
        return;
    }
    int t2 = tid - 131072;
    if (t2 < 8704) {                           // W1p: kb 0..16, t 0..7, lane 0..63
        int kb   = t2 >> 9;
        int rem  = t2 & 511;
        int t    = rem >> 6;
        int lane = rem & 63;
        int row  = t * 16 + (lane & 15);
        int kbase = kb * 32 + (lane >> 4) * 8;
        s16x8 pk;
        #pragma unroll
        for (int j = 0; j < 8; ++j) {
            int kp = kbase + j;
            float val = 0.f;
            if (kp < 512) {                                          // feature weights
                int kk = kp >> 6, c = kp & 63;
                val = W1[row * 520 + kk * 65 + 1 + c];
            } else if (kp < 520) {                                   // dis weight of neighbor kp-512
                val = W1[row * 520 + (kp - 512) * 65];
            }
            pk[j] = (short)f2bf(val);
        }
        *(s16x8*)(w1p + (size_t)t2 * 8) = pk;
    } else if (t2 < 8704 + 2048) {             // W2p
        int f    = t2 - 8704;
        int kb   = f >> 9;
        int rem  = f & 511;
        int t    = rem >> 6;
        int lane = rem & 63;
        int row  = t * 16 + (lane & 15);
        int k    = kb * 32 + (lane >> 4) * 8;
        s16x8 pk;
        #pragma unroll
        for (int j = 0; j < 8; ++j) pk[j] = (short)f2bf(W2[row * 128 + k + j]);
        *(s16x8*)(w2p + (size_t)f * 8) = pk;
    } else if (t2 < 8704 + 2048 + 4096) {      // W3p
        int f    = t2 - 10752;
        int hk   = f >> 9;
        int half = hk >> 2, kb = hk & 3;
        int rem  = f & 511;
        int t    = rem >> 6;
        int lane = rem & 63;
        int row  = (half * 8 + t) * 16 + (lane & 15);
        int k    = kb * 32 + (lane >> 4) * 8;
        s16x8 pk;
        #pragma unroll
        for (int j = 0; j < 8; ++j) pk[j] = (short)f2bf(W3[row * 128 + k + j]);
        *(s16x8*)(w3p + (size_t)f * 8) = pk;
    }
}

// ---------------- main fused kernel helpers ----------------
__device__ __forceinline__ void wload4(const unsigned short* wp, int frag0, int lane,
                                       bf16x8& w0, bf16x8& w1, bf16x8& w2, bf16x8& w3)
{
    w0 = *(const bf16x8*)(wp + (size_t)((frag0 + 0) * 64 + lane) * 8);
    w1 = *(const bf16x8*)(wp + (size_t)((frag0 + 1) * 64 + lane) * 8);
    w2 = *(const bf16x8*)(wp + (size_t)((frag0 + 2) * 64 + lane) * 8);
    w3 = *(const bf16x8*)(wp + (size_t)((frag0 + 3) * 64 + lane) * 8);
}

// iq[] holds the CURRENT half of each point's idx row; swapped at the kb 7->8 boundary.
template <int KB>
__device__ __forceinline__ void gather4(const unsigned short* featB, const int4 (&iq)[4],
                                        int grp8, bf16x8& G0, bf16x8& G1, bf16x8& G2, bf16x8& G3)
{
    constexpr int kk = KB >> 1;
    constexpr int j  = kk & 3;
    const int c0 = (KB & 1) * 32 + grp8;
    G0 = *(const bf16x8*)(featB + (((size_t)(unsigned)getq(iq[0], j)) << 6) + c0);
    G1 = *(const bf16x8*)(featB + (((size_t)(unsigned)getq(iq[1], j)) << 6) + c0);
    G2 = *(const bf16x8*)(featB + (((size_t)(unsigned)getq(iq[2], j)) << 6) + c0);
    G3 = *(const bf16x8*)(featB + (((size_t)(unsigned)getq(iq[3], j)) << 6) + c0);
}

__device__ __forceinline__ void refresh_iq(int4 (&iq)[4], const int* ip0) {
    #pragma unroll
    for (int pt = 0; pt < 4; ++pt) iq[pt] = *(const int4*)(ip0 + pt * 128 + 4);   // hi half (kk 4..7)
}

// dis columns (kb=16 data): grp 0 lanes carry dis[0..7], other grps are zero pad
__device__ __forceinline__ void disload4(const unsigned short* disB, int p0, int l15, int grp,
                                         bf16x8& G0, bf16x8& G1, bf16x8& G2, bf16x8& G3)
{
    const s16x8 z = {0,0,0,0,0,0,0,0};
    if (grp == 0) {
        G0 = *(const bf16x8*)(disB + (size_t)(p0 +  0 + l15) * 8);
        G1 = *(const bf16x8*)(disB + (size_t)(p0 + 16 + l15) * 8);
        G2 = *(const bf16x8*)(disB + (size_t)(p0 + 32 + l15) * 8);
        G3 = *(const bf16x8*)(disB + (size_t)(p0 + 48 + l15) * 8);
    } else {
        G0 = __builtin_bit_cast(bf16x8, z); G1 = __builtin_bit_cast(bf16x8, z);
        G2 = __builtin_bit_cast(bf16x8, z); G3 = __builtin_bit_cast(bf16x8, z);
    }
}

__device__ __forceinline__ void dsread4(const unsigned short* strip, int kb, int l15, int grp8,
                                        bf16x8& G0, bf16x8& G1, bf16x8& G2, bf16x8& G3)
{
    G0 = *(const bf16x8*)(strip + (0 * 16 + l15) * 136 + kb * 32 + grp8);
    G1 = *(const bf16x8*)(strip + (1 * 16 + l15) * 136 + kb * 32 + grp8);
    G2 = *(const bf16x8*)(strip + (2 * 16 + l15) * 136 + kb * 32 + grp8);
    G3 = *(const bf16x8*)(strip + (3 * 16 + l15) * 136 + kb * 32 + grp8);
}

// 4 weight frags x 4 point-tiles = 16 MFMAs into acc[4][4]; setprio around the cluster.
__device__ __forceinline__ void mfma_q4(f32x4 (&ac)[4][4],
    const bf16x8& w0, const bf16x8& w1, const bf16x8& w2, const bf16x8& w3,
    const bf16x8& B0, const bf16x8& B1, const bf16x8& B2, const bf16x8& B3)
{
    __builtin_amdgcn_s_setprio(1);
    ac[0][0] = __builtin_amdgcn_mfma_f32_16x16x32_bf16(w0, B0, ac[0][0], 0, 0, 0);
    ac[0][1] = __builtin_amdgcn_mfma_f32_16x16x32_bf16(w0, B1, ac[0][1], 0, 0, 0);
    ac[0][2] = __builtin_amdgcn_mfma_f32_16x16x32_bf16(w0, B2, ac[0][2], 0, 0, 0);
    ac[0][3] = __builtin_amdgcn_mfma_f32_16x16x32_bf16(w0, B3, ac[0][3], 0, 0, 0);
    ac[1][0] = __builtin_amdgcn_mfma_f32_16x16x32_bf16(w1, B0, ac[1][0], 0, 0, 0);
    ac[1][1] = __builtin_amdgcn_mfma_f32_16x16x32_bf16(w1, B1, ac[1][1], 0, 0, 0);
    ac[1][2] = __builtin_amdgcn_mfma_f32_16x16x32_bf16(w1, B2, ac[1][2], 0, 0, 0);
    ac[1][3] = __builtin_amdgcn_mfma_f32_16x16x32_bf16(w1, B3, ac[1][3], 0, 0, 0);
    ac[2][0] = __builtin_amdgcn_mfma_f32_16x16x32_bf16(w2, B0, ac[2][0], 0, 0, 0);
    ac[2][1] = __builtin_amdgcn_mfma_f32_16x16x32_bf16(w2, B1, ac[2][1], 0, 0, 0);
    ac[2][2] = __builtin_amdgcn_mfma_f32_16x16x32_bf16(w2, B2, ac[2][2], 0, 0, 0);
    ac[2][3] = __builtin_amdgcn_mfma_f32_16x16x32_bf16(w2, B3, ac[2][3], 0, 0, 0);
    ac[3][0] = __builtin_amdgcn_mfma_f32_16x16x32_bf16(w3, B0, ac[3][0], 0, 0, 0);
    ac[3][1] = __builtin_amdgcn_mfma_f32_16x16x32_bf16(w3, B1, ac[3][1], 0, 0, 0);
    ac[3][2] = __builtin_amdgcn_mfma_f32_16x16x32_bf16(w3, B2, ac[3][2], 0, 0, 0);
    ac[3][3] = __builtin_amdgcn_mfma_f32_16x16x32_bf16(w3, B3, ac[3][3], 0, 0, 0);
    __builtin_amdgcn_s_setprio(0);
}

// ---------------- main fused kernel ----------------
// 2 waves (128 thr) per block, 64 pts/block; CHANNELS split across waves:
// wave wv owns t-frags [wv*4, wv*4+4) in GEMM1/GEMM2 (64 ch) and half=wv of GEMM3
// (128 ch, done in two 64-ch passes). Peak acc = [4][4] = 64 AGPR -> ~170 unified
// regs -> 3 waves/SIMD resident (grid supplies 4). Shared H strip, 3 barriers.
__global__ __launch_bounds__(128, 3) void pointconv_main(
    const unsigned short* __restrict__ featT,
    const unsigned short* __restrict__ disB,
    const int* __restrict__ idx,
    const unsigned short* __restrict__ w1p,
    const unsigned short* __restrict__ w2p,
    const unsigned short* __restrict__ w3p,
    const float* __restrict__ b1, const float* __restrict__ b2,
    const float* __restrict__ b3, float* __restrict__ out)
{
    __shared__ __align__(16) unsigned short strip[64 * 136];   // 17,408 B shared by both waves
    const int bid  = blockIdx.x;
    const int wg   = (bid & 7) * 256 + (bid >> 3);     // XCD-aware bijective swizzle (2048 blocks)
    const int tid  = threadIdx.x;
    const int wv   = tid >> 6;                         // 0 or 1: channel half
    const int tw   = wv * 4;                           // t-frag base for this wave
    const int lane = tid & 63;
    const int grp  = lane >> 4;
    const int grp8 = grp * 8;
    const int l15  = lane & 15;
    const int p0   = wg * 64;
    const int b    = p0 >> 14;
    const int n0   = p0 & 16383;

    // pipeline registers
    bf16x8 gA0, gA1, gA2, gA3, gB0, gB1, gB2, gB3;     // B-frag double buffer
    bf16x8 wA0, wA1, wA2, wA3, wB0, wB1, wB2, wB3;     // weight quad double buffer

    // ---- prolog: kb0 weights for this wave's half, idx lo-half, first two gather sets ----
    wload4(w1p, 0 * 8 + tw, lane, wA0, wA1, wA2, wA3);

    const int* ip0 = idx + (size_t)(p0 + l15) * 8;
    int4 iq[4];
    #pragma unroll
    for (int pt = 0; pt < 4; ++pt) iq[pt] = *(const int4*)(ip0 + pt * 128);   // kk 0..3

    const unsigned short* featB = featT + ((size_t)b << 20);

    gather4<0>(featB, iq, grp8, gA0, gA1, gA2, gA3);
    gather4<1>(featB, iq, grp8, gB0, gB1, gB2, gB3);

    // ================= GEMM1: this wave computes 64 of 128 channels =================
    f32x4 acc[4][4];
    #pragma unroll
    for (int t = 0; t < 4; ++t)
        #pragma unroll
        for (int pt = 0; pt < 4; ++pt) acc[t][pt] = (f32x4){0.f, 0.f, 0.f, 0.f};

// even steps use wA/gA, odd use wB/gB; prefetch next kb's quad into the partner.
// GNEXT stays AFTER the mfma (it overwrites the g-set mfma just read — WAR rule from R11).
#define G1_E(KB, GNEXT)                                                     \
    wload4(w1p, (KB + 1) * 8 + tw, lane, wB0, wB1, wB2, wB3);               \
    mfma_q4(acc, wA0, wA1, wA2, wA3, gA0, gA1, gA2, gA3);                   \
    GNEXT;
#define G1_O(KB, GNEXT)                                                     \
    wload4(w1p, (KB + 1) * 8 + tw, lane, wA0, wA1, wA2, wA3);               \
    mfma_q4(acc, wB0, wB1, wB2, wB3, gB0, gB1, gB2, gB3);                   \
    GNEXT;

    G1_E(0,  (gather4< 2>(featB, iq, grp8, gA0,gA1,gA2,gA3)))
    G1_O(1,  (gather4< 3>(featB, iq, grp8, gB0,gB1,gB2,gB3)))
    G1_E(2,  (gather4< 4>(featB, iq, grp8, gA0,gA1,gA2,gA3)))
    G1_O(3,  (gather4< 5>(featB, iq, grp8, gB0,gB1,gB2,gB3)))
    G1_E(4,  (gather4< 6>(featB, iq, grp8, gA0,gA1,gA2,gA3)))
    G1_O(5,  (gather4< 7>(featB, iq, grp8, gB0,gB1,gB2,gB3)))
    refresh_iq(iq, ip0);                                // swap to hi half (kk 4..7)
    G1_E(6,  (gather4< 8>(featB, iq, grp8, gA0,gA1,gA2,gA3)))
    G1_O(7,  (gather4< 9>(featB, iq, grp8, gB0,gB1,gB2,gB3)))
    G1_E(8,  (gather4<10>(featB, iq, grp8, gA0,gA1,gA2,gA3)))
    G1_O(9,  (gather4<11>(featB, iq, grp8, gB0,gB1,gB2,gB3)))
    G1_E(10, (gather4<12>(featB, iq, grp8, gA0,gA1,gA2,gA3)))
    G1_O(11, (gather4<13>(featB, iq, grp8, gB0,gB1,gB2,gB3)))
    G1_E(12, (gather4<14>(featB, iq, grp8, gA0,gA1,gA2,gA3)))
    G1_O(13, (gather4<15>(featB, iq, grp8, gB0,gB1,gB2,gB3)))
    G1_E(14, disload4(disB, p0, l15, grp, gA0,gA1,gA2,gA3))   // gA <- dis cols (kb16 data)
    G1_O(15, )
    // kb=16 (even, dis/zero cols); prefetch chains into GEMM2's kb0 quad (this wave's half)
    wload4(w2p, 0 * 8 + tw, lane, wB0, wB1, wB2, wB3);
    mfma_q4(acc, wA0, wA1, wA2, wA3, gA0, gA1, gA2, gA3);
#undef G1_E
#undef G1_O

    // epilogue 1: bias + relu -> strip cols [wv*64, wv*64+64)
    #pragma unroll
    for (int t = 0; t < 4; ++t) {
        const int chb = (tw + t) * 16 + grp * 4;
        const float4 bv = *(const float4*)(b1 + chb);
        #pragma unroll
        for (int pt = 0; pt < 4; ++pt) {
            s16x4 pk;
            float v0 = acc[t][pt][0] + bv.x; pk[0] = (short)f2bf(v0 > 0.f ? v0 : 0.f);
            float v1 = acc[t][pt][1] + bv.y; pk[1] = (short)f2bf(v1 > 0.f ? v1 : 0.f);
            float v2 = acc[t][pt][2] + bv.z; pk[2] = (short)f2bf(v2 > 0.f ? v2 : 0.f);
            float v3 = acc[t][pt][3] + bv.w; pk[3] = (short)f2bf(v3 > 0.f ? v3 : 0.f);
            *(s16x4*)(strip + (pt * 16 + l15) * 136 + chb) = pk;
        }
    }
    __syncthreads();                                   // B1: full H1 resident

    // ================= GEMM2: this wave computes 64 of 128 channels, full K=128 =================
    f32x4 acc2[4][4];
    #pragma unroll
    for (int t = 0; t < 4; ++t)
        #pragma unroll
        for (int pt = 0; pt < 4; ++pt) acc2[t][pt] = (f32x4){0.f, 0.f, 0.f, 0.f};

    dsread4(strip, 0, l15, grp8, gA0, gA1, gA2, gA3);

    // step0 (uses wB=w2p kb0): prefetch kb1->wA, dsread kb1->gB
    wload4(w2p, 1 * 8 + tw, lane, wA0, wA1, wA2, wA3);
    dsread4(strip, 1, l15, grp8, gB0, gB1, gB2, gB3);
    mfma_q4(acc2, wB0, wB1, wB2, wB3, gA0, gA1, gA2, gA3);
    // step1: prefetch kb2->wB, dsread kb2->gA
    wload4(w2p, 2 * 8 + tw, lane, wB0, wB1, wB2, wB3);
    dsread4(strip, 2, l15, grp8, gA0, gA1, gA2, gA3);
    mfma_q4(acc2, wA0, wA1, wA2, wA3, gB0, gB1, gB2, gB3);
    // step2: prefetch kb3->wA, dsread kb3->gB
    wload4(w2p, 3 * 8 + tw, lane, wA0, wA1, wA2, wA3);
    dsread4(strip, 3, l15, grp8, gB0, gB1, gB2, gB3);
    mfma_q4(acc2, wB0, wB1, wB2, wB3, gA0, gA1, gA2, gA3);
    // step3: prefetch GEMM3 pass0 kb0 quad -> wB ; frag0 = (tw+0)*8 + 0
    wload4(w3p, tw * 8, lane, wB0, wB1, wB2, wB3);
    mfma_q4(acc2, wA0, wA1, wA2, wA3, gB0, gB1, gB2, gB3);

    __syncthreads();                                   // B2: all H1 reads done (lgkmcnt drained)

    // epilogue 2: bias + relu -> strip cols [wv*64, wv*64+64)  (H2 overwrites H1)
    #pragma unroll
    for (int t = 0; t < 4; ++t) {
        const int chb = (tw + t) * 16 + grp * 4;
        const float4 bv = *(const float4*)(b2 + chb);
        #pragma unroll
        for (int pt = 0; pt < 4; ++pt) {
            s16x4 pk;
            float v0 = acc2[t][pt][0] + bv.x; pk[0] = (short)f2bf(v0 > 0.f ? v0 : 0.f);
            float v1 = acc2[t][pt][1] + bv.y; pk[1] = (short)f2bf(v1 > 0.f ? v1 : 0.f);
            float v2 = acc2[t][pt][2] + bv.z; pk[2] = (short)f2bf(v2 > 0.f ? v2 : 0.f);
            float v3 = acc2[t][pt][3] + bv.w; pk[3] = (short)f2bf(v3 > 0.f ? v3 : 0.f);
            *(s16x4*)(strip + (pt * 16 + l15) * 136 + chb) = pk;
        }
    }
    __syncthreads();                                   // B3: full H2 resident

    // ================= GEMM3: this wave computes ch [wv*128, wv*128+128) in 2 passes =================
    // frag id for pass p, kb: (tw + kb)*8 + p*4   (4 consecutive t frags per wload4)
    #pragma unroll
    for (int p = 0; p < 2; ++p) {
        f32x4 acc3[4][4];
        #pragma unroll
        for (int t = 0; t < 4; ++t)
            #pragma unroll
            for (int pt = 0; pt < 4; ++pt) acc3[t][pt] = (f32x4){0.f, 0.f, 0.f, 0.f};

        dsread4(strip, 0, l15, grp8, gA0, gA1, gA2, gA3);
        // step0 (uses wB = pass-p kb0 quad, prefetched): prefetch kb1->wA, dsread kb1->gB
        wload4(w3p, (tw + 1) * 8 + p * 4, lane, wA0, wA1, wA2, wA3);
        dsread4(strip, 1, l15, grp8, gB0, gB1, gB2, gB3);
        mfma_q4(acc3, wB0, wB1, wB2, wB3, gA0, gA1, gA2, gA3);
        // step1: prefetch kb2->wB, dsread kb2->gA
        wload4(w3p, (tw + 2) * 8 + p * 4, lane, wB0, wB1, wB2, wB3);
        dsread4(strip, 2, l15, grp8, gA0, gA1, gA2, gA3);
        mfma_q4(acc3, wA0, wA1, wA2, wA3, gB0, gB1, gB2, gB3);
        // step2: prefetch kb3->wA, dsread kb3->gB
        wload4(w3p, (tw + 3) * 8 + p * 4, lane, wA0, wA1, wA2, wA3);
        dsread4(strip, 3, l15, grp8, gB0, gB1, gB2, gB3);
        mfma_q4(acc3, wB0, wB1, wB2, wB3, gA0, gA1, gA2, gA3);
        // step3: prefetch pass1 kb0 -> wB (only needed when p==0); compute with wA
        if (p == 0) wload4(w3p, tw * 8 + 4, lane, wB0, wB1, wB2, wB3);
        mfma_q4(acc3, wA0, wA1, wA2, wA3, gB0, gB1, gB2, gB3);

        #pragma unroll
        for (int t = 0; t < 4; ++t) {
            const int ch0 = wv * 128 + p * 64 + t * 16 + grp * 4;
            const float4 bv = *(const float4*)(b3 + ch0);
            #pragma unroll
            for (int pt = 0; pt < 4; ++pt) {
                const int n = n0 + pt * 16 + l15;
                float* op = out + (((size_t)(b * 256 + ch0)) << 14) + n;
                op[0]                  = acc3[t][pt][0] + bv.x;
                op[(size_t)1 << 14]    = acc3[t][pt][1] + bv.y;
                op[(size_t)2 << 14]    = acc3[t][pt][2] + bv.z;
                op[(size_t)3 << 14]    = acc3[t][pt][3] + bv.w;
            }
        }
    }
}

extern "C" void kernel_launch(void* const* d_in, const int* in_sizes, int n_in,
                              void* d_out, int out_size, void* d_ws, size_t ws_size,
                              hipStream_t stream)
{
    const float* feature = (const float*)d_in[0];
    const int*   idx     = (const int*)d_in[1];
    const float* dis     = (const float*)d_in[2];
    const float* W1      = (const float*)d_in[3];
    const float* b1      = (const float*)d_in[4];
    const float* W2      = (const float*)d_in[5];
    const float* b2      = (const float*)d_in[6];
    const float* W3      = (const float*)d_in[7];
    const float* b3      = (const float*)d_in[8];
    float* out = (float*)d_out;

    char* ws = (char*)d_ws;
    unsigned short* featT = (unsigned short*)ws;
    unsigned short* disB  = (unsigned short*)(ws + OFF_DISB);
    unsigned short* w1p   = (unsigned short*)(ws + OFF_W1B);
    unsigned short* w2p   = (unsigned short*)(ws + OFF_W2B);
    unsigned short* w3p   = (unsigned short*)(ws + OFF_W3B);

    hipLaunchKernelGGL(prep_all, dim3(1488), dim3(256), 0, stream,
                       feature, dis, W1, W2, W3, featT, disB, w1p, w2p, w3p);
    hipLaunchKernelGGL(pointconv_main, dim3(2048), dim3(128), 0, stream,
                       featT, disB, idx, w1p, w2p, w3p, b1, b2, b3, out);
}